// Round 1
// baseline (1236.209 us; speedup 1.0000x reference)
//
#include <hip/hip_runtime.h>

#define N_NODES 100000
#define N_EDGES 1600000
#define N_FEAT  602
#define HIDDEN  128
#define N_CLS   41

// ---------------- degrees ----------------
__global__ void k_deg(const int* __restrict__ src, const int* __restrict__ dst,
                      int* __restrict__ deg_out, int* __restrict__ deg_in) {
    int e = blockIdx.x * blockDim.x + threadIdx.x;
    if (e < N_EDGES) {
        atomicAdd(&deg_out[src[e]], 1);
        atomicAdd(&deg_in[dst[e]], 1);
    }
}

__global__ void k_norm(const int* __restrict__ deg_out, const int* __restrict__ deg_in,
                       float* __restrict__ ns, float* __restrict__ nd) {
    int i = blockIdx.x * blockDim.x + threadIdx.x;
    if (i < N_NODES) {
        ns[i] = 1.0f / sqrtf((float)max(deg_out[i], 1));
        nd[i] = 1.0f / sqrtf((float)max(deg_in[i], 1));
    }
}

// ---------------- exclusive scan of deg_in -> row_ptr (3 kernels) ----------------
__global__ void k_scan1(const int* __restrict__ deg_in, int* __restrict__ row_ptr,
                        int* __restrict__ blk) {
    __shared__ int s[1024];
    int t = threadIdx.x;
    int i = blockIdx.x * 1024 + t;
    int v = (i < N_NODES) ? deg_in[i] : 0;
    s[t] = v; __syncthreads();
    for (int off = 1; off < 1024; off <<= 1) {
        int x = s[t];
        if (t >= off) x += s[t - off];
        __syncthreads();
        s[t] = x; __syncthreads();
    }
    if (i < N_NODES) row_ptr[i] = s[t] - v;      // exclusive within block
    if (t == 1023) blk[blockIdx.x] = s[1023];    // block total
}

__global__ void k_scan2(int* __restrict__ blk, int nblk) {
    __shared__ int s[128];
    int t = threadIdx.x;
    int v = (t < nblk) ? blk[t] : 0;
    s[t] = v; __syncthreads();
    for (int off = 1; off < 128; off <<= 1) {
        int x = s[t];
        if (t >= off) x += s[t - off];
        __syncthreads();
        s[t] = x; __syncthreads();
    }
    if (t < nblk) blk[t] = s[t] - v;             // exclusive block offsets
}

__global__ void k_scan3(int* __restrict__ row_ptr, const int* __restrict__ blk) {
    int i = blockIdx.x * blockDim.x + threadIdx.x;
    if (i < N_NODES) row_ptr[i] += blk[i >> 10];
}

// ---------------- CSR fill (bucket by dst) ----------------
__global__ void k_fill(const int* __restrict__ src, const int* __restrict__ dst,
                       const int* __restrict__ row_ptr, int* __restrict__ cursor,
                       int* __restrict__ csr_src) {
    int e = blockIdx.x * blockDim.x + threadIdx.x;
    if (e < N_EDGES) {
        int d = dst[e];
        int p = atomicAdd(&cursor[d], 1);
        csr_src[row_ptr[d] + p] = src[e];
    }
}

// ---------------- GEMM1: y1 = ns ⊙ (x @ W1)   [100000 x 128] ----------------
#define KT 32
__global__ __launch_bounds__(256) void k_gemm1(const float* __restrict__ x,
                                               const float* __restrict__ W1,
                                               const float* __restrict__ ns,
                                               float* __restrict__ y1) {
    __shared__ float sa[64][KT + 1];
    __shared__ float sw[KT][HIDDEN];
    int tid = threadIdx.x;
    int tx = tid & 15, ty = tid >> 4;          // 16 col-groups x 16 row-groups
    int m0 = blockIdx.x * 64;
    float acc[4][8];
    #pragma unroll
    for (int i = 0; i < 4; i++)
        #pragma unroll
        for (int j = 0; j < 8; j++) acc[i][j] = 0.f;

    for (int k0 = 0; k0 < N_FEAT; k0 += KT) {
        {   // stage A tile 64 x KT
            int kk = tid & 31, r0 = tid >> 5;
            #pragma unroll
            for (int it = 0; it < 8; ++it) {
                int r = r0 + it * 8;
                int row = m0 + r, k = k0 + kk;
                float v = 0.f;
                if (row < N_NODES && k < N_FEAT) v = x[(long)row * N_FEAT + k];
                sa[r][kk] = v;
            }
            // stage W tile KT x 128
            int c = tid & 127, kk2 = tid >> 7;
            #pragma unroll
            for (int it = 0; it < KT / 2; ++it) {
                int k = k0 + kk2 + it * 2;
                sw[kk2 + it * 2][c] = (k < N_FEAT) ? W1[(long)k * HIDDEN + c] : 0.f;
            }
        }
        __syncthreads();
        #pragma unroll 8
        for (int kk = 0; kk < KT; ++kk) {
            float a[4], w[8];
            #pragma unroll
            for (int i = 0; i < 4; i++) a[i] = sa[ty * 4 + i][kk];
            #pragma unroll
            for (int j = 0; j < 8; j++) w[j] = sw[kk][tx * 8 + j];
            #pragma unroll
            for (int i = 0; i < 4; i++)
                #pragma unroll
                for (int j = 0; j < 8; j++)
                    acc[i][j] = fmaf(a[i], w[j], acc[i][j]);
        }
        __syncthreads();
    }
    #pragma unroll
    for (int i = 0; i < 4; i++) {
        int row = m0 + ty * 4 + i;
        if (row < N_NODES) {
            float s = ns[row];
            #pragma unroll
            for (int j = 0; j < 8; j++)
                y1[(long)row * HIDDEN + tx * 8 + j] = acc[i][j] * s;
        }
    }
}

// ---------------- SpMM1 + epilogue: h1 = relu(A@y1 * nd + b1)  [100000 x 128] ----------------
__global__ __launch_bounds__(256) void k_spmm1(const float* __restrict__ y1,
                                               const int* __restrict__ row_ptr,
                                               const int* __restrict__ deg_in,
                                               const int* __restrict__ csr_src,
                                               const float* __restrict__ nd,
                                               const float* __restrict__ b1,
                                               float* __restrict__ h1) {
    int wave = threadIdx.x >> 6, lane = threadIdx.x & 63;
    int n = blockIdx.x * 4 + wave;
    if (n >= N_NODES) return;
    int base = row_ptr[n], deg = deg_in[n];
    float a0 = 0.f, a1 = 0.f;
    for (int j = 0; j < deg; ++j) {
        int s = csr_src[base + j];
        float2 v = ((const float2*)(y1 + (long)s * HIDDEN))[lane];
        a0 += v.x; a1 += v.y;
    }
    float d = nd[n];
    float2 b = ((const float2*)b1)[lane];
    float2 r;
    r.x = fmaxf(a0 * d + b.x, 0.f);
    r.y = fmaxf(a1 * d + b.y, 0.f);
    ((float2*)(h1 + (long)n * HIDDEN))[lane] = r;
}

// ---------------- GEMM2: y2 = ns ⊙ (h1 @ W2)   [100000 x 41] ----------------
__global__ __launch_bounds__(256) void k_gemm2(const float* __restrict__ h1,
                                               const float* __restrict__ W2,
                                               const float* __restrict__ ns,
                                               float* __restrict__ y2) {
    __shared__ float sz[64 * 132];
    __shared__ float sw[128 * 44];
    int tid = threadIdx.x;
    int m0 = blockIdx.x * 64;
    for (int idx = tid; idx < 128 * 44; idx += 256) {
        int k = idx / 44, c = idx % 44;
        sw[idx] = (c < N_CLS) ? W2[k * N_CLS + c] : 0.f;
    }
    for (int idx = tid; idx < 64 * 32; idx += 256) {
        int r = idx >> 5, q = idx & 31;
        int row = m0 + r;
        float4 v = make_float4(0.f, 0.f, 0.f, 0.f);
        if (row < N_NODES) v = ((const float4*)h1)[(long)row * 32 + q];
        *((float4*)&sz[r * 132 + q * 4]) = v;
    }
    __syncthreads();
    int r = tid >> 2, cq = tid & 3;
    int c0 = cq * 11;
    float acc[11];
    #pragma unroll
    for (int j = 0; j < 11; j++) acc[j] = 0.f;
    #pragma unroll 8
    for (int k = 0; k < 128; ++k) {
        float a = sz[r * 132 + k];
        #pragma unroll
        for (int j = 0; j < 11; j++) acc[j] = fmaf(a, sw[k * 44 + c0 + j], acc[j]);
    }
    int row = m0 + r;
    if (row < N_NODES) {
        float s = ns[row];
        #pragma unroll
        for (int j = 0; j < 11; j++) {
            int c = c0 + j;
            if (c < N_CLS) y2[(long)row * N_CLS + c] = acc[j] * s;
        }
    }
}

// ---------------- SpMM2 + epilogue: out = A@y2 * nd + b2   [100000 x 41] ----------------
__global__ __launch_bounds__(256) void k_spmm2(const float* __restrict__ y2,
                                               const int* __restrict__ row_ptr,
                                               const int* __restrict__ deg_in,
                                               const int* __restrict__ csr_src,
                                               const float* __restrict__ nd,
                                               const float* __restrict__ b2,
                                               float* __restrict__ out) {
    int wave = threadIdx.x >> 6, lane = threadIdx.x & 63;
    int n = blockIdx.x * 4 + wave;
    if (n >= N_NODES) return;
    if (lane >= N_CLS) return;
    int base = row_ptr[n], deg = deg_in[n];
    float a = 0.f;
    for (int j = 0; j < deg; ++j) {
        int s = csr_src[base + j];
        a += y2[(long)s * N_CLS + lane];
    }
    out[(long)n * N_CLS + lane] = a * nd[n] + b2[lane];
}

extern "C" void kernel_launch(void* const* d_in, const int* in_sizes, int n_in,
                              void* d_out, int out_size, void* d_ws, size_t ws_size,
                              hipStream_t stream) {
    const float* x    = (const float*)d_in[0];
    const int*   esrc = (const int*)d_in[1];
    const int*   edst = (const int*)d_in[2];
    const float* W1   = (const float*)d_in[3];
    const float* b1   = (const float*)d_in[4];
    const float* W2   = (const float*)d_in[5];
    const float* b2   = (const float*)d_in[6];
    float* out = (float*)d_out;

    char* p = (char*)d_ws;
    auto alloc = [&](size_t bytes) {
        char* r = p;
        p += (bytes + 255) & ~(size_t)255;
        return r;
    };
    int*   deg_out = (int*)alloc((size_t)N_NODES * 4);
    int*   deg_in  = (int*)alloc((size_t)N_NODES * 4);
    float* ns      = (float*)alloc((size_t)N_NODES * 4);
    float* nd      = (float*)alloc((size_t)N_NODES * 4);
    int*   row_ptr = (int*)alloc((size_t)N_NODES * 4);
    int*   cursor  = (int*)alloc((size_t)N_NODES * 4);
    int*   blk     = (int*)alloc(1024 * 4);
    int*   csr     = (int*)alloc((size_t)N_EDGES * 4);
    float* y1      = (float*)alloc((size_t)N_NODES * HIDDEN * 4);  // reused as y2
    float* h1      = (float*)alloc((size_t)N_NODES * HIDDEN * 4);
    float* y2      = y1;  // y1 dead after spmm1; y2 (16.4MB) fits in its 51.2MB
    if ((size_t)(p - (char*)d_ws) > ws_size) return;  // ws too small — fail visibly

    hipMemsetAsync(deg_out, 0, (size_t)N_NODES * 4, stream);
    hipMemsetAsync(deg_in,  0, (size_t)N_NODES * 4, stream);
    hipMemsetAsync(cursor,  0, (size_t)N_NODES * 4, stream);

    const int EB = (N_EDGES + 255) / 256;       // 6250
    const int NB = (N_NODES + 255) / 256;       // 391
    const int SB = (N_NODES + 1023) / 1024;     // 98
    const int MB = (N_NODES + 63) / 64;         // 1563

    k_deg<<<EB, 256, 0, stream>>>(esrc, edst, deg_out, deg_in);
    k_norm<<<NB, 256, 0, stream>>>(deg_out, deg_in, ns, nd);
    k_scan1<<<SB, 1024, 0, stream>>>(deg_in, row_ptr, blk);
    k_scan2<<<1, 128, 0, stream>>>(blk, SB);
    k_scan3<<<NB, 256, 0, stream>>>(row_ptr, blk);
    k_fill<<<EB, 256, 0, stream>>>(esrc, edst, row_ptr, cursor, csr);
    k_gemm1<<<MB, 256, 0, stream>>>(x, W1, ns, y1);
    k_spmm1<<<(N_NODES + 3) / 4, 256, 0, stream>>>(y1, row_ptr, deg_in, csr, nd, b1, h1);
    k_gemm2<<<MB, 256, 0, stream>>>(h1, W2, ns, y2);
    k_spmm2<<<(N_NODES + 3) / 4, 256, 0, stream>>>(y2, row_ptr, deg_in, csr, nd, b2, out);
}

// Round 2
// 1111.475 us; speedup vs baseline: 1.1122x; 1.1122x over previous
//
#include <hip/hip_runtime.h>

#define N_NODES 100000
#define N_EDGES 1600000
#define N_FEAT  602
#define HIDDEN  128
#define N_CLS   41

typedef __attribute__((ext_vector_type(8))) short bf16x8;
typedef __attribute__((ext_vector_type(8))) unsigned short u16x8;
typedef __attribute__((ext_vector_type(4))) float f32x4;

#define LDSTRIDE 40   // bf16 elements per LDS row (32 data + 8 pad -> 80B, 16B-aligned rows)
#define KPAD 608      // 19 * 32

// bf16 round-to-nearest-even, returns hi and residual
__device__ inline unsigned short bf_hi(float f, float& rem) {
    unsigned int u = __float_as_uint(f);
    unsigned int r = u + 0x7FFF + ((u >> 16) & 1);
    unsigned short h = (unsigned short)(r >> 16);
    rem = f - __uint_as_float((unsigned int)h << 16);
    return h;
}
__device__ inline unsigned short bf_rn(float f) {
    unsigned int u = __float_as_uint(f);
    unsigned int r = u + 0x7FFF + ((u >> 16) & 1);
    return (unsigned short)(r >> 16);
}

// ---------------- degrees ----------------
__global__ void k_deg(const int* __restrict__ src, const int* __restrict__ dst,
                      int* __restrict__ deg_out, int* __restrict__ deg_in) {
    int e = blockIdx.x * blockDim.x + threadIdx.x;
    if (e < N_EDGES) {
        atomicAdd(&deg_out[src[e]], 1);
        atomicAdd(&deg_in[dst[e]], 1);
    }
}

__global__ void k_norm(const int* __restrict__ deg_out, const int* __restrict__ deg_in,
                       float* __restrict__ ns, float* __restrict__ nd) {
    int i = blockIdx.x * blockDim.x + threadIdx.x;
    if (i < N_NODES) {
        ns[i] = 1.0f / sqrtf((float)max(deg_out[i], 1));
        nd[i] = 1.0f / sqrtf((float)max(deg_in[i], 1));
    }
}

// ---------------- W1 convert: fp32 [602][128] -> transposed bf16 hi/lo [128][608] ----------------
__global__ void k_wconv(const float* __restrict__ W1,
                        unsigned short* __restrict__ Wt_hi,
                        unsigned short* __restrict__ Wt_lo) {
    int c = blockIdx.x;          // 0..127 output column
    int k = threadIdx.x;         // 0..639
    if (k >= KPAD) return;
    float w = (k < N_FEAT) ? W1[(long)k * HIDDEN + c] : 0.f;
    float rem;
    unsigned short h = bf_hi(w, rem);
    Wt_hi[(long)c * KPAD + k] = h;
    Wt_lo[(long)c * KPAD + k] = bf_rn(rem);
}

// ---------------- exclusive scan of deg_in -> row_ptr (3 kernels) ----------------
__global__ void k_scan1(const int* __restrict__ deg_in, int* __restrict__ row_ptr,
                        int* __restrict__ blk) {
    __shared__ int s[1024];
    int t = threadIdx.x;
    int i = blockIdx.x * 1024 + t;
    int v = (i < N_NODES) ? deg_in[i] : 0;
    s[t] = v; __syncthreads();
    for (int off = 1; off < 1024; off <<= 1) {
        int x = s[t];
        if (t >= off) x += s[t - off];
        __syncthreads();
        s[t] = x; __syncthreads();
    }
    if (i < N_NODES) row_ptr[i] = s[t] - v;
    if (t == 1023) blk[blockIdx.x] = s[1023];
}

__global__ void k_scan2(int* __restrict__ blk, int nblk) {
    __shared__ int s[128];
    int t = threadIdx.x;
    int v = (t < nblk) ? blk[t] : 0;
    s[t] = v; __syncthreads();
    for (int off = 1; off < 128; off <<= 1) {
        int x = s[t];
        if (t >= off) x += s[t - off];
        __syncthreads();
        s[t] = x; __syncthreads();
    }
    if (t < nblk) blk[t] = s[t] - v;
}

__global__ void k_scan3(int* __restrict__ row_ptr, const int* __restrict__ blk) {
    int i = blockIdx.x * blockDim.x + threadIdx.x;
    if (i < N_NODES) row_ptr[i] += blk[i >> 10];
}

// ---------------- CSR fill (bucket by dst) ----------------
__global__ void k_fill(const int* __restrict__ src, const int* __restrict__ dst,
                       const int* __restrict__ row_ptr, int* __restrict__ cursor,
                       int* __restrict__ csr_src) {
    int e = blockIdx.x * blockDim.x + threadIdx.x;
    if (e < N_EDGES) {
        int d = dst[e];
        int p = atomicAdd(&cursor[d], 1);
        csr_src[row_ptr[d] + p] = src[e];
    }
}

// ---------------- GEMM1 (split-bf16 MFMA): y1 = ns ⊙ (x @ W1)  [100000 x 128] ----------------
// Block: 128 rows x 128 cols, 4 waves in 2x2, wave = 64x64 = 4x4 tiles of 16x16x32 MFMA.
__global__ __launch_bounds__(256) void k_gemm1(const float* __restrict__ x,
                                               const unsigned short* __restrict__ Wt_hi,
                                               const unsigned short* __restrict__ Wt_lo,
                                               const float* __restrict__ ns,
                                               float* __restrict__ y1) {
    __shared__ __align__(16) unsigned short As_hi[128 * LDSTRIDE];
    __shared__ __align__(16) unsigned short As_lo[128 * LDSTRIDE];
    __shared__ __align__(16) unsigned short Bs_hi[128 * LDSTRIDE];
    __shared__ __align__(16) unsigned short Bs_lo[128 * LDSTRIDE];

    int tid = threadIdx.x;
    int lane = tid & 63;
    int wave = tid >> 6;
    int quad = lane >> 4, l16 = lane & 15;
    int wm = wave >> 1, wn = wave & 1;
    int m0 = blockIdx.x * 128;

    f32x4 acc[4][4];
    #pragma unroll
    for (int i = 0; i < 4; i++)
        #pragma unroll
        for (int j = 0; j < 4; j++)
            acc[i][j] = (f32x4){0.f, 0.f, 0.f, 0.f};

    int sr = tid >> 1;      // 0..127: A-row index / B-col index
    int sh = tid & 1;       // k half (16 elements each)

    const int arow = m0 + sr;
    const bool rowok = arow < N_NODES;
    const float* xrow = x + (long)arow * N_FEAT;

    for (int kt = 0; kt < 19; ++kt) {
        int k0 = kt * 32;
        // ---- stage A: load 16 fp32, split into bf16 hi/lo ----
        {
            int kb = k0 + sh * 16;
            #pragma unroll
            for (int i = 0; i < 4; ++i) {
                float v[4];
                #pragma unroll
                for (int p = 0; p < 2; ++p) {
                    int k = kb + i * 4 + p * 2;
                    float2 t = make_float2(0.f, 0.f);
                    if (rowok && k < N_FEAT) t = *(const float2*)(xrow + k);  // 602 even: k<602 => k+1<602
                    v[p * 2] = t.x; v[p * 2 + 1] = t.y;
                }
                ushort4 ph, pl;
                float r0, r1, r2, r3;
                ph.x = bf_hi(v[0], r0); ph.y = bf_hi(v[1], r1);
                ph.z = bf_hi(v[2], r2); ph.w = bf_hi(v[3], r3);
                pl.x = bf_rn(r0); pl.y = bf_rn(r1); pl.z = bf_rn(r2); pl.w = bf_rn(r3);
                int off = sr * LDSTRIDE + sh * 16 + i * 4;
                *(ushort4*)&As_hi[off] = ph;
                *(ushort4*)&As_lo[off] = pl;
            }
        }
        // ---- stage B: straight bf16 16B loads from pre-converted Wt ----
        {
            long gb = (long)sr * KPAD + k0 + sh * 16;
            int off = sr * LDSTRIDE + sh * 16;
            u16x8 b0 = *(const u16x8*)(Wt_hi + gb);
            u16x8 b1 = *(const u16x8*)(Wt_hi + gb + 8);
            *(u16x8*)&Bs_hi[off]     = b0;
            *(u16x8*)&Bs_hi[off + 8] = b1;
            u16x8 c0 = *(const u16x8*)(Wt_lo + gb);
            u16x8 c1 = *(const u16x8*)(Wt_lo + gb + 8);
            *(u16x8*)&Bs_lo[off]     = c0;
            *(u16x8*)&Bs_lo[off + 8] = c1;
        }
        __syncthreads();
        #pragma unroll
        for (int mi = 0; mi < 4; ++mi) {
            int ar = (wm * 64 + mi * 16 + l16) * LDSTRIDE + quad * 8;
            bf16x8 ah = *(bf16x8*)&As_hi[ar];
            bf16x8 al = *(bf16x8*)&As_lo[ar];
            #pragma unroll
            for (int ni = 0; ni < 4; ++ni) {
                int br = (wn * 64 + ni * 16 + l16) * LDSTRIDE + quad * 8;
                bf16x8 bh = *(bf16x8*)&Bs_hi[br];
                bf16x8 bl = *(bf16x8*)&Bs_lo[br];
                acc[mi][ni] = __builtin_amdgcn_mfma_f32_16x16x32_bf16(ah, bh, acc[mi][ni], 0, 0, 0);
                acc[mi][ni] = __builtin_amdgcn_mfma_f32_16x16x32_bf16(al, bh, acc[mi][ni], 0, 0, 0);
                acc[mi][ni] = __builtin_amdgcn_mfma_f32_16x16x32_bf16(ah, bl, acc[mi][ni], 0, 0, 0);
            }
        }
        __syncthreads();
    }

    // epilogue: C/D layout col=lane&15, row=quad*4+reg
    #pragma unroll
    for (int mi = 0; mi < 4; ++mi) {
        #pragma unroll
        for (int r = 0; r < 4; ++r) {
            int row = m0 + wm * 64 + mi * 16 + quad * 4 + r;
            if (row < N_NODES) {
                float s = ns[row];
                #pragma unroll
                for (int ni = 0; ni < 4; ++ni) {
                    int col = wn * 64 + ni * 16 + l16;
                    y1[(long)row * HIDDEN + col] = acc[mi][ni][r] * s;
                }
            }
        }
    }
}

// ---------------- SpMM1 + epilogue: h1 = relu(A@y1 * nd + b1)  [100000 x 128] ----------------
__global__ __launch_bounds__(256) void k_spmm1(const float* __restrict__ y1,
                                               const int* __restrict__ row_ptr,
                                               const int* __restrict__ deg_in,
                                               const int* __restrict__ csr_src,
                                               const float* __restrict__ nd,
                                               const float* __restrict__ b1,
                                               float* __restrict__ h1) {
    int wave = threadIdx.x >> 6, lane = threadIdx.x & 63;
    int n = blockIdx.x * 4 + wave;
    if (n >= N_NODES) return;
    int base = row_ptr[n], deg = deg_in[n];
    float a0 = 0.f, a1 = 0.f;
    for (int j = 0; j < deg; ++j) {
        int s = csr_src[base + j];
        float2 v = ((const float2*)(y1 + (long)s * HIDDEN))[lane];
        a0 += v.x; a1 += v.y;
    }
    float d = nd[n];
    float2 b = ((const float2*)b1)[lane];
    float2 r;
    r.x = fmaxf(a0 * d + b.x, 0.f);
    r.y = fmaxf(a1 * d + b.y, 0.f);
    ((float2*)(h1 + (long)n * HIDDEN))[lane] = r;
}

// ---------------- GEMM2: y2 = ns ⊙ (h1 @ W2)   [100000 x 41] ----------------
__global__ __launch_bounds__(256) void k_gemm2(const float* __restrict__ h1,
                                               const float* __restrict__ W2,
                                               const float* __restrict__ ns,
                                               float* __restrict__ y2) {
    __shared__ float sz[64 * 132];
    __shared__ float sw[128 * 44];
    int tid = threadIdx.x;
    int m0 = blockIdx.x * 64;
    for (int idx = tid; idx < 128 * 44; idx += 256) {
        int k = idx / 44, c = idx % 44;
        sw[idx] = (c < N_CLS) ? W2[k * N_CLS + c] : 0.f;
    }
    for (int idx = tid; idx < 64 * 32; idx += 256) {
        int r = idx >> 5, q = idx & 31;
        int row = m0 + r;
        float4 v = make_float4(0.f, 0.f, 0.f, 0.f);
        if (row < N_NODES) v = ((const float4*)h1)[(long)row * 32 + q];
        *((float4*)&sz[r * 132 + q * 4]) = v;
    }
    __syncthreads();
    int r = tid >> 2, cq = tid & 3;
    int c0 = cq * 11;
    float acc[11];
    #pragma unroll
    for (int j = 0; j < 11; j++) acc[j] = 0.f;
    #pragma unroll 8
    for (int k = 0; k < 128; ++k) {
        float a = sz[r * 132 + k];
        #pragma unroll
        for (int j = 0; j < 11; j++) acc[j] = fmaf(a, sw[k * 44 + c0 + j], acc[j]);
    }
    int row = m0 + r;
    if (row < N_NODES) {
        float s = ns[row];
        #pragma unroll
        for (int j = 0; j < 11; j++) {
            int c = c0 + j;
            if (c < N_CLS) y2[(long)row * N_CLS + c] = acc[j] * s;
        }
    }
}

// ---------------- SpMM2 + epilogue: out = A@y2 * nd + b2   [100000 x 41] ----------------
__global__ __launch_bounds__(256) void k_spmm2(const float* __restrict__ y2,
                                               const int* __restrict__ row_ptr,
                                               const int* __restrict__ deg_in,
                                               const int* __restrict__ csr_src,
                                               const float* __restrict__ nd,
                                               const float* __restrict__ b2,
                                               float* __restrict__ out) {
    int wave = threadIdx.x >> 6, lane = threadIdx.x & 63;
    int n = blockIdx.x * 4 + wave;
    if (n >= N_NODES) return;
    if (lane >= N_CLS) return;
    int base = row_ptr[n], deg = deg_in[n];
    float a = 0.f;
    for (int j = 0; j < deg; ++j) {
        int s = csr_src[base + j];
        a += y2[(long)s * N_CLS + lane];
    }
    out[(long)n * N_CLS + lane] = a * nd[n] + b2[lane];
}

extern "C" void kernel_launch(void* const* d_in, const int* in_sizes, int n_in,
                              void* d_out, int out_size, void* d_ws, size_t ws_size,
                              hipStream_t stream) {
    const float* x    = (const float*)d_in[0];
    const int*   esrc = (const int*)d_in[1];
    const int*   edst = (const int*)d_in[2];
    const float* W1   = (const float*)d_in[3];
    const float* b1   = (const float*)d_in[4];
    const float* W2   = (const float*)d_in[5];
    const float* b2   = (const float*)d_in[6];
    float* out = (float*)d_out;

    char* p = (char*)d_ws;
    auto alloc = [&](size_t bytes) {
        char* r = p;
        p += (bytes + 255) & ~(size_t)255;
        return r;
    };
    int*   deg_out = (int*)alloc((size_t)N_NODES * 4);
    int*   deg_in  = (int*)alloc((size_t)N_NODES * 4);
    float* ns      = (float*)alloc((size_t)N_NODES * 4);
    float* nd      = (float*)alloc((size_t)N_NODES * 4);
    int*   row_ptr = (int*)alloc((size_t)N_NODES * 4);
    int*   cursor  = (int*)alloc((size_t)N_NODES * 4);
    int*   blk     = (int*)alloc(1024 * 4);
    unsigned short* Wt_hi = (unsigned short*)alloc((size_t)HIDDEN * KPAD * 2);
    unsigned short* Wt_lo = (unsigned short*)alloc((size_t)HIDDEN * KPAD * 2);
    int*   csr     = (int*)alloc((size_t)N_EDGES * 4);
    float* y1      = (float*)alloc((size_t)N_NODES * HIDDEN * 4);  // reused as y2
    float* h1      = (float*)alloc((size_t)N_NODES * HIDDEN * 4);
    float* y2      = y1;  // y1 dead after spmm1
    if ((size_t)(p - (char*)d_ws) > ws_size) return;

    hipMemsetAsync(deg_out, 0, (size_t)N_NODES * 4, stream);
    hipMemsetAsync(deg_in,  0, (size_t)N_NODES * 4, stream);
    hipMemsetAsync(cursor,  0, (size_t)N_NODES * 4, stream);

    const int EB = (N_EDGES + 255) / 256;       // 6250
    const int NB = (N_NODES + 255) / 256;       // 391
    const int SB = (N_NODES + 1023) / 1024;     // 98
    const int MB = (N_NODES + 127) / 128;       // 782

    k_deg<<<EB, 256, 0, stream>>>(esrc, edst, deg_out, deg_in);
    k_norm<<<NB, 256, 0, stream>>>(deg_out, deg_in, ns, nd);
    k_wconv<<<HIDDEN, 640, 0, stream>>>(W1, Wt_hi, Wt_lo);
    k_scan1<<<SB, 1024, 0, stream>>>(deg_in, row_ptr, blk);
    k_scan2<<<1, 128, 0, stream>>>(blk, SB);
    k_scan3<<<NB, 256, 0, stream>>>(row_ptr, blk);
    k_fill<<<EB, 256, 0, stream>>>(esrc, edst, row_ptr, cursor, csr);
    k_gemm1<<<MB, 256, 0, stream>>>(x, Wt_hi, Wt_lo, ns, y1);
    k_spmm1<<<(N_NODES + 3) / 4, 256, 0, stream>>>(y1, row_ptr, deg_in, csr, nd, b1, h1);
    k_gemm2<<<(N_NODES + 63) / 64, 256, 0, stream>>>(h1, W2, ns, y2);
    k_spmm2<<<(N_NODES + 3) / 4, 256, 0, stream>>>(y2, row_ptr, deg_in, csr, nd, b2, out);
}

// Round 3
// 1079.108 us; speedup vs baseline: 1.1456x; 1.0300x over previous
//
#include <hip/hip_runtime.h>

#define N_NODES 100000
#define N_EDGES 1600000
#define N_FEAT  602
#define HIDDEN  128
#define N_CLS   41

typedef __attribute__((ext_vector_type(8))) short bf16x8;
typedef __attribute__((ext_vector_type(8))) unsigned short u16x8;
typedef __attribute__((ext_vector_type(4))) float f32x4;

#define LDSTRIDE 40   // bf16 elements per LDS row (32 data + 8 pad -> 80B rows)
#define KPAD 608      // 19 * 32

// bf16 round-to-nearest-even, returns hi and residual
__device__ inline unsigned short bf_hi(float f, float& rem) {
    unsigned int u = __float_as_uint(f);
    unsigned int r = u + 0x7FFF + ((u >> 16) & 1);
    unsigned short h = (unsigned short)(r >> 16);
    rem = f - __uint_as_float((unsigned int)h << 16);
    return h;
}
__device__ inline unsigned short bf_rn(float f) {
    unsigned int u = __float_as_uint(f);
    unsigned int r = u + 0x7FFF + ((u >> 16) & 1);
    return (unsigned short)(r >> 16);
}

// ---------------- degrees ----------------
__global__ void k_deg(const int* __restrict__ src, const int* __restrict__ dst,
                      int* __restrict__ deg_out, int* __restrict__ deg_in) {
    int e = blockIdx.x * blockDim.x + threadIdx.x;
    if (e < N_EDGES) {
        atomicAdd(&deg_out[src[e]], 1);
        atomicAdd(&deg_in[dst[e]], 1);
    }
}

__global__ void k_norm(const int* __restrict__ deg_out, const int* __restrict__ deg_in,
                       float* __restrict__ ns, float* __restrict__ nd) {
    int i = blockIdx.x * blockDim.x + threadIdx.x;
    if (i < N_NODES) {
        ns[i] = 1.0f / sqrtf((float)max(deg_out[i], 1));
        nd[i] = 1.0f / sqrtf((float)max(deg_in[i], 1));
    }
}

// ---------------- W1 convert: fp32 [602][128] -> transposed bf16 hi/lo [128][608] ----------------
__global__ void k_wconv(const float* __restrict__ W1,
                        unsigned short* __restrict__ Wt_hi,
                        unsigned short* __restrict__ Wt_lo) {
    int c = blockIdx.x;
    int k = threadIdx.x;
    if (k >= KPAD) return;
    float w = (k < N_FEAT) ? W1[(long)k * HIDDEN + c] : 0.f;
    float rem;
    unsigned short h = bf_hi(w, rem);
    Wt_hi[(long)c * KPAD + k] = h;
    Wt_lo[(long)c * KPAD + k] = bf_rn(rem);
}

// ---------------- exclusive scan of deg_in -> row_ptr ----------------
__global__ void k_scan1(const int* __restrict__ deg_in, int* __restrict__ row_ptr,
                        int* __restrict__ blk) {
    __shared__ int s[1024];
    int t = threadIdx.x;
    int i = blockIdx.x * 1024 + t;
    int v = (i < N_NODES) ? deg_in[i] : 0;
    s[t] = v; __syncthreads();
    for (int off = 1; off < 1024; off <<= 1) {
        int x = s[t];
        if (t >= off) x += s[t - off];
        __syncthreads();
        s[t] = x; __syncthreads();
    }
    if (i < N_NODES) row_ptr[i] = s[t] - v;
    if (t == 1023) blk[blockIdx.x] = s[1023];
}

__global__ void k_scan2(int* __restrict__ blk, int nblk) {
    __shared__ int s[128];
    int t = threadIdx.x;
    int v = (t < nblk) ? blk[t] : 0;
    s[t] = v; __syncthreads();
    for (int off = 1; off < 128; off <<= 1) {
        int x = s[t];
        if (t >= off) x += s[t - off];
        __syncthreads();
        s[t] = x; __syncthreads();
    }
    if (t < nblk) blk[t] = s[t] - v;
}

__global__ void k_scan3(int* __restrict__ row_ptr, const int* __restrict__ blk) {
    int i = blockIdx.x * blockDim.x + threadIdx.x;
    if (i < N_NODES) row_ptr[i] += blk[i >> 10];
}

// ---------------- CSR fill (bucket by dst) ----------------
__global__ void k_fill(const int* __restrict__ src, const int* __restrict__ dst,
                       const int* __restrict__ row_ptr, int* __restrict__ cursor,
                       int* __restrict__ csr_src) {
    int e = blockIdx.x * blockDim.x + threadIdx.x;
    if (e < N_EDGES) {
        int d = dst[e];
        int p = atomicAdd(&cursor[d], 1);
        csr_src[row_ptr[d] + p] = src[e];
    }
}

// ---------------- GEMM1 (split-bf16 MFMA, pipelined): y1 = ns ⊙ (x @ W1) ----------------
// Block: 128x128, 4 waves 2x2, wave = 64x64 via 4x4 tiles of 16x16x32 MFMA, K-tiles of 32.
__global__ __launch_bounds__(256, 4) void k_gemm1(const float* __restrict__ x,
                                                  const unsigned short* __restrict__ Wt_hi,
                                                  const unsigned short* __restrict__ Wt_lo,
                                                  const float* __restrict__ ns,
                                                  float* __restrict__ y1) {
    __shared__ __align__(16) unsigned short As_hi[128 * LDSTRIDE];
    __shared__ __align__(16) unsigned short As_lo[128 * LDSTRIDE];
    __shared__ __align__(16) unsigned short Bs_hi[128 * LDSTRIDE];
    __shared__ __align__(16) unsigned short Bs_lo[128 * LDSTRIDE];

    int tid = threadIdx.x;
    int lane = tid & 63;
    int wave = tid >> 6;
    int quad = lane >> 4, l16 = lane & 15;
    int wm = wave >> 1, wn = wave & 1;
    int m0 = blockIdx.x * 128;

    f32x4 acc[4][4];
    #pragma unroll
    for (int i = 0; i < 4; i++)
        #pragma unroll
        for (int j = 0; j < 4; j++)
            acc[i][j] = (f32x4){0.f, 0.f, 0.f, 0.f};

    // A staging: thread t -> rows (t>>3)+32i, float4 chunk (t&7). 8 lanes = 128B of one row.
    const int ar = tid >> 3, ac = tid & 7;
    // B staging: thread t -> rows (t>>2)+64j, u16x8 chunk (t&3). 4 lanes = 64B of one row.
    const int bc = tid >> 2, bch = tid & 3;

    float4 pa[4];
    u16x8  pbh[2], pbl[2];

    auto loadA = [&](int k0, float4 (&dst)[4]) {
        #pragma unroll
        for (int i = 0; i < 4; ++i) {
            int row = m0 + ar + 32 * i;
            int k = k0 + ac * 4;
            float4 v = make_float4(0.f, 0.f, 0.f, 0.f);
            if (row < N_NODES) {
                const float* xp = x + (long)row * N_FEAT + k;
                if (k + 4 <= N_FEAT) {
                    v = *(const float4*)xp;         // 8B-aligned; dwordx4 ok at dword align
                } else if (k < N_FEAT) {            // only last tile, chunk 6 (k=600)
                    v.x = xp[0];
                    if (k + 1 < N_FEAT) v.y = xp[1];
                }
            }
            dst[i] = v;
        }
    };
    auto loadB = [&](int k0, u16x8 (&dh)[2], u16x8 (&dl)[2]) {
        #pragma unroll
        for (int j = 0; j < 2; ++j) {
            long g = (long)(bc + 64 * j) * KPAD + k0 + bch * 8;
            dh[j] = *(const u16x8*)(Wt_hi + g);
            dl[j] = *(const u16x8*)(Wt_lo + g);
        }
    };

    loadA(0, pa);
    loadB(0, pbh, pbl);

    for (int kt = 0; kt < 19; ++kt) {
        // ---- stage prefetched tile into LDS ----
        #pragma unroll
        for (int i = 0; i < 4; ++i) {
            float4 v = pa[i];
            ushort4 h, l;
            float r0, r1, r2, r3;
            h.x = bf_hi(v.x, r0); h.y = bf_hi(v.y, r1);
            h.z = bf_hi(v.z, r2); h.w = bf_hi(v.w, r3);
            l.x = bf_rn(r0); l.y = bf_rn(r1); l.z = bf_rn(r2); l.w = bf_rn(r3);
            int off = (ar + 32 * i) * LDSTRIDE + ac * 4;
            *(ushort4*)&As_hi[off] = h;
            *(ushort4*)&As_lo[off] = l;
        }
        #pragma unroll
        for (int j = 0; j < 2; ++j) {
            int off = (bc + 64 * j) * LDSTRIDE + bch * 8;
            *(u16x8*)&Bs_hi[off] = pbh[j];
            *(u16x8*)&Bs_lo[off] = pbl[j];
        }
        __syncthreads();

        // ---- issue next tile's global loads (consumed after next barrier) ----
        float4 na[4];
        u16x8  nbh[2], nbl[2];
        if (kt < 18) {
            loadA((kt + 1) * 32, na);
            loadB((kt + 1) * 32, nbh, nbl);
        }

        // ---- MFMA on current LDS tile (overlaps the loads above) ----
        #pragma unroll
        for (int mi = 0; mi < 4; ++mi) {
            int arr = (wm * 64 + mi * 16 + l16) * LDSTRIDE + quad * 8;
            bf16x8 ah = *(bf16x8*)&As_hi[arr];
            bf16x8 al = *(bf16x8*)&As_lo[arr];
            #pragma unroll
            for (int ni = 0; ni < 4; ++ni) {
                int br = (wn * 64 + ni * 16 + l16) * LDSTRIDE + quad * 8;
                bf16x8 bh = *(bf16x8*)&Bs_hi[br];
                bf16x8 bl = *(bf16x8*)&Bs_lo[br];
                acc[mi][ni] = __builtin_amdgcn_mfma_f32_16x16x32_bf16(ah, bh, acc[mi][ni], 0, 0, 0);
                acc[mi][ni] = __builtin_amdgcn_mfma_f32_16x16x32_bf16(al, bh, acc[mi][ni], 0, 0, 0);
                acc[mi][ni] = __builtin_amdgcn_mfma_f32_16x16x32_bf16(ah, bl, acc[mi][ni], 0, 0, 0);
            }
        }
        __syncthreads();

        if (kt < 18) {
            #pragma unroll
            for (int i = 0; i < 4; ++i) pa[i] = na[i];
            #pragma unroll
            for (int j = 0; j < 2; ++j) { pbh[j] = nbh[j]; pbl[j] = nbl[j]; }
        }
    }

    // epilogue: C/D layout col=lane&15, row=quad*4+reg
    #pragma unroll
    for (int mi = 0; mi < 4; ++mi) {
        #pragma unroll
        for (int r = 0; r < 4; ++r) {
            int row = m0 + wm * 64 + mi * 16 + quad * 4 + r;
            if (row < N_NODES) {
                float s = ns[row];
                #pragma unroll
                for (int ni = 0; ni < 4; ++ni) {
                    int col = wn * 64 + ni * 16 + l16;
                    y1[(long)row * HIDDEN + col] = acc[mi][ni][r] * s;
                }
            }
        }
    }
}

// ---------------- SpMM1 + epilogue: h1 = relu(A@y1 * nd + b1) ----------------
__global__ __launch_bounds__(256) void k_spmm1(const float* __restrict__ y1,
                                               const int* __restrict__ row_ptr,
                                               const int* __restrict__ deg_in,
                                               const int* __restrict__ csr_src,
                                               const float* __restrict__ nd,
                                               const float* __restrict__ b1,
                                               float* __restrict__ h1) {
    int wave = threadIdx.x >> 6, lane = threadIdx.x & 63;
    int n = blockIdx.x * 4 + wave;
    if (n >= N_NODES) return;
    int base = row_ptr[n], deg = deg_in[n];
    float a0 = 0.f, a1 = 0.f;
    for (int j = 0; j < deg; ++j) {
        int s = csr_src[base + j];
        float2 v = ((const float2*)(y1 + (long)s * HIDDEN))[lane];
        a0 += v.x; a1 += v.y;
    }
    float d = nd[n];
    float2 b = ((const float2*)b1)[lane];
    float2 r;
    r.x = fmaxf(a0 * d + b.x, 0.f);
    r.y = fmaxf(a1 * d + b.y, 0.f);
    ((float2*)(h1 + (long)n * HIDDEN))[lane] = r;
}

// ---------------- GEMM2: y2 = ns ⊙ (h1 @ W2) ----------------
__global__ __launch_bounds__(256) void k_gemm2(const float* __restrict__ h1,
                                               const float* __restrict__ W2,
                                               const float* __restrict__ ns,
                                               float* __restrict__ y2) {
    __shared__ float sz[64 * 132];
    __shared__ float sw[128 * 44];
    int tid = threadIdx.x;
    int m0 = blockIdx.x * 64;
    for (int idx = tid; idx < 128 * 44; idx += 256) {
        int k = idx / 44, c = idx % 44;
        sw[idx] = (c < N_CLS) ? W2[k * N_CLS + c] : 0.f;
    }
    for (int idx = tid; idx < 64 * 32; idx += 256) {
        int r = idx >> 5, q = idx & 31;
        int row = m0 + r;
        float4 v = make_float4(0.f, 0.f, 0.f, 0.f);
        if (row < N_NODES) v = ((const float4*)h1)[(long)row * 32 + q];
        *((float4*)&sz[r * 132 + q * 4]) = v;
    }
    __syncthreads();
    int r = tid >> 2, cq = tid & 3;
    int c0 = cq * 11;
    float acc[11];
    #pragma unroll
    for (int j = 0; j < 11; j++) acc[j] = 0.f;
    #pragma unroll 8
    for (int k = 0; k < 128; ++k) {
        float a = sz[r * 132 + k];
        #pragma unroll
        for (int j = 0; j < 11; j++) acc[j] = fmaf(a, sw[k * 44 + c0 + j], acc[j]);
    }
    int row = m0 + r;
    if (row < N_NODES) {
        float s = ns[row];
        #pragma unroll
        for (int j = 0; j < 11; j++) {
            int c = c0 + j;
            if (c < N_CLS) y2[(long)row * N_CLS + c] = acc[j] * s;
        }
    }
}

// ---------------- SpMM2 + epilogue: out = A@y2 * nd + b2 ----------------
__global__ __launch_bounds__(256) void k_spmm2(const float* __restrict__ y2,
                                               const int* __restrict__ row_ptr,
                                               const int* __restrict__ deg_in,
                                               const int* __restrict__ csr_src,
                                               const float* __restrict__ nd,
                                               const float* __restrict__ b2,
                                               float* __restrict__ out) {
    int wave = threadIdx.x >> 6, lane = threadIdx.x & 63;
    int n = blockIdx.x * 4 + wave;
    if (n >= N_NODES) return;
    if (lane >= N_CLS) return;
    int base = row_ptr[n], deg = deg_in[n];
    float a = 0.f;
    for (int j = 0; j < deg; ++j) {
        int s = csr_src[base + j];
        a += y2[(long)s * N_CLS + lane];
    }
    out[(long)n * N_CLS + lane] = a * nd[n] + b2[lane];
}

extern "C" void kernel_launch(void* const* d_in, const int* in_sizes, int n_in,
                              void* d_out, int out_size, void* d_ws, size_t ws_size,
                              hipStream_t stream) {
    const float* x    = (const float*)d_in[0];
    const int*   esrc = (const int*)d_in[1];
    const int*   edst = (const int*)d_in[2];
    const float* W1   = (const float*)d_in[3];
    const float* b1   = (const float*)d_in[4];
    const float* W2   = (const float*)d_in[5];
    const float* b2   = (const float*)d_in[6];
    float* out = (float*)d_out;

    char* p = (char*)d_ws;
    auto alloc = [&](size_t bytes) {
        char* r = p;
        p += (bytes + 255) & ~(size_t)255;
        return r;
    };
    int*   deg_out = (int*)alloc((size_t)N_NODES * 4);
    int*   deg_in  = (int*)alloc((size_t)N_NODES * 4);
    float* ns      = (float*)alloc((size_t)N_NODES * 4);
    float* nd      = (float*)alloc((size_t)N_NODES * 4);
    int*   row_ptr = (int*)alloc((size_t)N_NODES * 4);
    int*   cursor  = (int*)alloc((size_t)N_NODES * 4);
    int*   blk     = (int*)alloc(1024 * 4);
    unsigned short* Wt_hi = (unsigned short*)alloc((size_t)HIDDEN * KPAD * 2);
    unsigned short* Wt_lo = (unsigned short*)alloc((size_t)HIDDEN * KPAD * 2);
    int*   csr     = (int*)alloc((size_t)N_EDGES * 4);
    float* y1      = (float*)alloc((size_t)N_NODES * HIDDEN * 4);  // reused as y2
    float* h1      = (float*)alloc((size_t)N_NODES * HIDDEN * 4);
    float* y2      = y1;
    if ((size_t)(p - (char*)d_ws) > ws_size) return;

    hipMemsetAsync(deg_out, 0, (size_t)N_NODES * 4, stream);
    hipMemsetAsync(deg_in,  0, (size_t)N_NODES * 4, stream);
    hipMemsetAsync(cursor,  0, (size_t)N_NODES * 4, stream);

    const int EB = (N_EDGES + 255) / 256;
    const int NB = (N_NODES + 255) / 256;
    const int SB = (N_NODES + 1023) / 1024;
    const int MB = (N_NODES + 127) / 128;

    k_deg<<<EB, 256, 0, stream>>>(esrc, edst, deg_out, deg_in);
    k_norm<<<NB, 256, 0, stream>>>(deg_out, deg_in, ns, nd);
    k_wconv<<<HIDDEN, 640, 0, stream>>>(W1, Wt_hi, Wt_lo);
    k_scan1<<<SB, 1024, 0, stream>>>(deg_in, row_ptr, blk);
    k_scan2<<<1, 128, 0, stream>>>(blk, SB);
    k_scan3<<<NB, 256, 0, stream>>>(row_ptr, blk);
    k_fill<<<EB, 256, 0, stream>>>(esrc, edst, row_ptr, cursor, csr);
    k_gemm1<<<MB, 256, 0, stream>>>(x, Wt_hi, Wt_lo, ns, y1);
    k_spmm1<<<(N_NODES + 3) / 4, 256, 0, stream>>>(y1, row_ptr, deg_in, csr, nd, b1, h1);
    k_gemm2<<<(N_NODES + 63) / 64, 256, 0, stream>>>(h1, W2, ns, y2);
    k_spmm2<<<(N_NODES + 3) / 4, 256, 0, stream>>>(y2, row_ptr, deg_in, csr, nd, b2, out);
}

// Round 4
// 1048.864 us; speedup vs baseline: 1.1786x; 1.0288x over previous
//
#include <hip/hip_runtime.h>

#define N_NODES 100000
#define N_EDGES 1600000
#define N_FEAT  602
#define HIDDEN  128
#define N_CLS   41

typedef __attribute__((ext_vector_type(8))) short bf16x8;
typedef __attribute__((ext_vector_type(8))) unsigned short u16x8;
typedef __attribute__((ext_vector_type(4))) float f32x4;

#define KPAD 608      // 19 * 32

typedef const __attribute__((address_space(1))) void gv_t;
typedef __attribute__((address_space(3))) void lv_t;

// bf16 round-to-nearest-even, returns hi and residual
__device__ inline unsigned short bf_hi(float f, float& rem) {
    unsigned int u = __float_as_uint(f);
    unsigned int r = u + 0x7FFF + ((u >> 16) & 1);
    unsigned short h = (unsigned short)(r >> 16);
    rem = f - __uint_as_float((unsigned int)h << 16);
    return h;
}
__device__ inline unsigned short bf_rn(float f) {
    unsigned int u = __float_as_uint(f);
    unsigned int r = u + 0x7FFF + ((u >> 16) & 1);
    return (unsigned short)(r >> 16);
}

// ---------------- degrees ----------------
__global__ void k_deg(const int* __restrict__ src, const int* __restrict__ dst,
                      int* __restrict__ deg_out, int* __restrict__ deg_in) {
    int e = blockIdx.x * blockDim.x + threadIdx.x;
    if (e < N_EDGES) {
        atomicAdd(&deg_out[src[e]], 1);
        atomicAdd(&deg_in[dst[e]], 1);
    }
}

__global__ void k_norm(const int* __restrict__ deg_out, const int* __restrict__ deg_in,
                       float* __restrict__ ns, float* __restrict__ nd) {
    int i = blockIdx.x * blockDim.x + threadIdx.x;
    if (i < N_NODES) {
        ns[i] = 1.0f / sqrtf((float)max(deg_out[i], 1));
        nd[i] = 1.0f / sqrtf((float)max(deg_in[i], 1));
    }
}

// ---------------- W1 convert: fp32 [602][128] -> transposed bf16 hi/lo [128][608] ----------------
__global__ void k_wconv(const float* __restrict__ W1,
                        unsigned short* __restrict__ Wt_hi,
                        unsigned short* __restrict__ Wt_lo) {
    int c = blockIdx.x;
    int k = threadIdx.x;
    if (k >= KPAD) return;
    float w = (k < N_FEAT) ? W1[(long)k * HIDDEN + c] : 0.f;
    float rem;
    unsigned short h = bf_hi(w, rem);
    Wt_hi[(long)c * KPAD + k] = h;
    Wt_lo[(long)c * KPAD + k] = bf_rn(rem);
}

// ---------------- exclusive scan of deg_in -> row_ptr ----------------
__global__ void k_scan1(const int* __restrict__ deg_in, int* __restrict__ row_ptr,
                        int* __restrict__ blk) {
    __shared__ int s[1024];
    int t = threadIdx.x;
    int i = blockIdx.x * 1024 + t;
    int v = (i < N_NODES) ? deg_in[i] : 0;
    s[t] = v; __syncthreads();
    for (int off = 1; off < 1024; off <<= 1) {
        int x = s[t];
        if (t >= off) x += s[t - off];
        __syncthreads();
        s[t] = x; __syncthreads();
    }
    if (i < N_NODES) row_ptr[i] = s[t] - v;
    if (t == 1023) blk[blockIdx.x] = s[1023];
}

__global__ void k_scan2(int* __restrict__ blk, int nblk) {
    __shared__ int s[128];
    int t = threadIdx.x;
    int v = (t < nblk) ? blk[t] : 0;
    s[t] = v; __syncthreads();
    for (int off = 1; off < 128; off <<= 1) {
        int x = s[t];
        if (t >= off) x += s[t - off];
        __syncthreads();
        s[t] = x; __syncthreads();
    }
    if (t < nblk) blk[t] = s[t] - v;
}

__global__ void k_scan3(int* __restrict__ row_ptr, const int* __restrict__ blk) {
    int i = blockIdx.x * blockDim.x + threadIdx.x;
    if (i < N_NODES) row_ptr[i] += blk[i >> 10];
}

// ---------------- CSR fill (bucket by dst) ----------------
__global__ void k_fill(const int* __restrict__ src, const int* __restrict__ dst,
                       const int* __restrict__ row_ptr, int* __restrict__ cursor,
                       int* __restrict__ csr_src) {
    int e = blockIdx.x * blockDim.x + threadIdx.x;
    if (e < N_EDGES) {
        int d = dst[e];
        int p = atomicAdd(&cursor[d], 1);
        csr_src[row_ptr[d] + p] = src[e];
    }
}

// ---------------- GEMM1 (split-bf16 MFMA, global_load_lds staging) ----------------
// y1 = ns ⊙ (x @ W1). Block 128x128, 4 waves 2x2, wave 64x64 = 4x4 of 16x16x32.
// A staged as raw fp32 (packed [row][32], 16KB); hi/lo split at fragment-read time.
// B staged as precomputed bf16 hi/lo (packed [col][32], 8KB each).
__global__ __launch_bounds__(256, 4) void k_gemm1(const float* __restrict__ x,
                                                  const unsigned short* __restrict__ Wt_hi,
                                                  const unsigned short* __restrict__ Wt_lo,
                                                  const float* __restrict__ ns,
                                                  float* __restrict__ y1) {
    __shared__ __align__(16) float          Af[128 * 32];   // 16 KB
    __shared__ __align__(16) unsigned short Bh[128 * 32];   // 8 KB
    __shared__ __align__(16) unsigned short Bl[128 * 32];   // 8 KB

    int tid = threadIdx.x;
    int lane = tid & 63;
    int wave = tid >> 6;
    int quad = lane >> 4, l16 = lane & 15;
    int wm = wave >> 1, wn = wave & 1;
    int m0 = blockIdx.x * 128;

    f32x4 acc[4][4];
    #pragma unroll
    for (int i = 0; i < 4; i++)
        #pragma unroll
        for (int j = 0; j < 4; j++)
            acc[i][j] = (f32x4){0.f, 0.f, 0.f, 0.f};

    // A staging addresses: instr i, lane l -> row = wave*32 + i*8 + l/8, chunk = l%8 (16B of fp32)
    int a_row = wave * 32 + (lane >> 3);           // +8*i
    int a_chn = lane & 7;
    // B staging: instr i, lane l -> col = wave*32 + i*16 + l/4, chunk = l%4 (16B of bf16)
    int b_col = wave * 32 + (lane >> 2);           // +16*i
    int b_chn = lane & 3;

    for (int kt = 0; kt < 19; ++kt) {
        int k0 = kt * 32;
        // ---- async global -> LDS staging (8 x 16B per thread) ----
        #pragma unroll
        for (int i = 0; i < 4; ++i) {
            int row = a_row + i * 8;
            int rowg = min(m0 + row, N_NODES - 1);          // clamp: keep addresses valid
            const float* gp = x + (long)rowg * N_FEAT + k0 + a_chn * 4;
            __builtin_amdgcn_global_load_lds((gv_t*)gp, (lv_t*)&Af[wave * 1024 + i * 256], 16, 0, 0);
        }
        #pragma unroll
        for (int i = 0; i < 2; ++i) {
            int col = b_col + i * 16;
            long g = (long)col * KPAD + k0 + b_chn * 8;
            __builtin_amdgcn_global_load_lds((gv_t*)(Wt_hi + g), (lv_t*)&Bh[wave * 1024 + i * 512], 16, 0, 0);
            __builtin_amdgcn_global_load_lds((gv_t*)(Wt_lo + g), (lv_t*)&Bl[wave * 1024 + i * 512], 16, 0, 0);
        }
        __syncthreads();   // compiler emits vmcnt(0) drain before barrier

        if (kt == 18) {
            // zero A columns k=602..607 (garbage read past row end); B is zero there,
            // but NaN-pattern garbage * 0 = NaN, so A must be clean too.
            for (int idx = tid; idx < 128 * 6; idx += 256) {
                int r = idx / 6, c = 26 + idx % 6;
                Af[r * 32 + c] = 0.f;
            }
            __syncthreads();
        }

        // ---- fragments + MFMA ----
        #pragma unroll
        for (int mi = 0; mi < 4; ++mi) {
            int arow = wm * 64 + mi * 16 + l16;
            const float* ap = &Af[arow * 32 + quad * 8];
            f32x4 v0 = *(const f32x4*)ap;
            f32x4 v1 = *(const f32x4*)(ap + 4);
            bf16x8 ah, al;
            float rem;
            #pragma unroll
            for (int j = 0; j < 4; ++j) {
                ah[j] = (short)bf_hi(v0[j], rem); al[j] = (short)bf_rn(rem);
            }
            #pragma unroll
            for (int j = 0; j < 4; ++j) {
                ah[4 + j] = (short)bf_hi(v1[j], rem); al[4 + j] = (short)bf_rn(rem);
            }
            #pragma unroll
            for (int ni = 0; ni < 4; ++ni) {
                int bcol = wn * 64 + ni * 16 + l16;
                bf16x8 bh = *(bf16x8*)&Bh[bcol * 32 + quad * 8];
                bf16x8 bl = *(bf16x8*)&Bl[bcol * 32 + quad * 8];
                acc[mi][ni] = __builtin_amdgcn_mfma_f32_16x16x32_bf16(ah, bh, acc[mi][ni], 0, 0, 0);
                acc[mi][ni] = __builtin_amdgcn_mfma_f32_16x16x32_bf16(al, bh, acc[mi][ni], 0, 0, 0);
                acc[mi][ni] = __builtin_amdgcn_mfma_f32_16x16x32_bf16(ah, bl, acc[mi][ni], 0, 0, 0);
            }
        }
        __syncthreads();
    }

    // epilogue: C/D layout col=lane&15, row=quad*4+reg
    #pragma unroll
    for (int mi = 0; mi < 4; ++mi) {
        #pragma unroll
        for (int r = 0; r < 4; ++r) {
            int row = m0 + wm * 64 + mi * 16 + quad * 4 + r;
            if (row < N_NODES) {
                float s = ns[row];
                #pragma unroll
                for (int ni = 0; ni < 4; ++ni) {
                    int col = wn * 64 + ni * 16 + l16;
                    y1[(long)row * HIDDEN + col] = acc[mi][ni][r] * s;
                }
            }
        }
    }
}

// ---------------- SpMM1 + epilogue: h1 = relu(A@y1 * nd + b1) ----------------
__global__ __launch_bounds__(256) void k_spmm1(const float* __restrict__ y1,
                                               const int* __restrict__ row_ptr,
                                               const int* __restrict__ deg_in,
                                               const int* __restrict__ csr_src,
                                               const float* __restrict__ nd,
                                               const float* __restrict__ b1,
                                               float* __restrict__ h1) {
    int wave = threadIdx.x >> 6, lane = threadIdx.x & 63;
    int n = blockIdx.x * 4 + wave;
    if (n >= N_NODES) return;
    int base = row_ptr[n], deg = deg_in[n];
    float a0 = 0.f, a1 = 0.f;
    for (int j = 0; j < deg; ++j) {
        int s = csr_src[base + j];
        float2 v = ((const float2*)(y1 + (long)s * HIDDEN))[lane];
        a0 += v.x; a1 += v.y;
    }
    float d = nd[n];
    float2 b = ((const float2*)b1)[lane];
    float2 r;
    r.x = fmaxf(a0 * d + b.x, 0.f);
    r.y = fmaxf(a1 * d + b.y, 0.f);
    ((float2*)(h1 + (long)n * HIDDEN))[lane] = r;
}

// ---------------- GEMM2: y2 = ns ⊙ (h1 @ W2) ----------------
__global__ __launch_bounds__(256) void k_gemm2(const float* __restrict__ h1,
                                               const float* __restrict__ W2,
                                               const float* __restrict__ ns,
                                               float* __restrict__ y2) {
    __shared__ float sz[64 * 132];
    __shared__ float sw[128 * 44];
    int tid = threadIdx.x;
    int m0 = blockIdx.x * 64;
    for (int idx = tid; idx < 128 * 44; idx += 256) {
        int k = idx / 44, c = idx % 44;
        sw[idx] = (c < N_CLS) ? W2[k * N_CLS + c] : 0.f;
    }
    for (int idx = tid; idx < 64 * 32; idx += 256) {
        int r = idx >> 5, q = idx & 31;
        int row = m0 + r;
        float4 v = make_float4(0.f, 0.f, 0.f, 0.f);
        if (row < N_NODES) v = ((const float4*)h1)[(long)row * 32 + q];
        *((float4*)&sz[r * 132 + q * 4]) = v;
    }
    __syncthreads();
    int r = tid >> 2, cq = tid & 3;
    int c0 = cq * 11;
    float acc[11];
    #pragma unroll
    for (int j = 0; j < 11; j++) acc[j] = 0.f;
    #pragma unroll 8
    for (int k = 0; k < 128; ++k) {
        float a = sz[r * 132 + k];
        #pragma unroll
        for (int j = 0; j < 11; j++) acc[j] = fmaf(a, sw[k * 44 + c0 + j], acc[j]);
    }
    int row = m0 + r;
    if (row < N_NODES) {
        float s = ns[row];
        #pragma unroll
        for (int j = 0; j < 11; j++) {
            int c = c0 + j;
            if (c < N_CLS) y2[(long)row * N_CLS + c] = acc[j] * s;
        }
    }
}

// ---------------- SpMM2 + epilogue: out = A@y2 * nd + b2 ----------------
__global__ __launch_bounds__(256) void k_spmm2(const float* __restrict__ y2,
                                               const int* __restrict__ row_ptr,
                                               const int* __restrict__ deg_in,
                                               const int* __restrict__ csr_src,
                                               const float* __restrict__ nd,
                                               const float* __restrict__ b2,
                                               float* __restrict__ out) {
    int wave = threadIdx.x >> 6, lane = threadIdx.x & 63;
    int n = blockIdx.x * 4 + wave;
    if (n >= N_NODES) return;
    if (lane >= N_CLS) return;
    int base = row_ptr[n], deg = deg_in[n];
    float a = 0.f;
    for (int j = 0; j < deg; ++j) {
        int s = csr_src[base + j];
        a += y2[(long)s * N_CLS + lane];
    }
    out[(long)n * N_CLS + lane] = a * nd[n] + b2[lane];
}

extern "C" void kernel_launch(void* const* d_in, const int* in_sizes, int n_in,
                              void* d_out, int out_size, void* d_ws, size_t ws_size,
                              hipStream_t stream) {
    const float* x    = (const float*)d_in[0];
    const int*   esrc = (const int*)d_in[1];
    const int*   edst = (const int*)d_in[2];
    const float* W1   = (const float*)d_in[3];
    const float* b1   = (const float*)d_in[4];
    const float* W2   = (const float*)d_in[5];
    const float* b2   = (const float*)d_in[6];
    float* out = (float*)d_out;

    char* p = (char*)d_ws;
    auto alloc = [&](size_t bytes) {
        char* r = p;
        p += (bytes + 255) & ~(size_t)255;
        return r;
    };
    int*   deg_out = (int*)alloc((size_t)N_NODES * 4);
    int*   deg_in  = (int*)alloc((size_t)N_NODES * 4);
    float* ns      = (float*)alloc((size_t)N_NODES * 4);
    float* nd      = (float*)alloc((size_t)N_NODES * 4);
    int*   row_ptr = (int*)alloc((size_t)N_NODES * 4);
    int*   cursor  = (int*)alloc((size_t)N_NODES * 4);
    int*   blk     = (int*)alloc(1024 * 4);
    unsigned short* Wt_hi = (unsigned short*)alloc((size_t)HIDDEN * KPAD * 2);
    unsigned short* Wt_lo = (unsigned short*)alloc((size_t)HIDDEN * KPAD * 2);
    int*   csr     = (int*)alloc((size_t)N_EDGES * 4);
    float* y1      = (float*)alloc((size_t)N_NODES * HIDDEN * 4);  // reused as y2
    float* h1      = (float*)alloc((size_t)N_NODES * HIDDEN * 4);
    float* y2      = y1;
    if ((size_t)(p - (char*)d_ws) > ws_size) return;

    hipMemsetAsync(deg_out, 0, (size_t)N_NODES * 4, stream);
    hipMemsetAsync(deg_in,  0, (size_t)N_NODES * 4, stream);
    hipMemsetAsync(cursor,  0, (size_t)N_NODES * 4, stream);

    const int EB = (N_EDGES + 255) / 256;
    const int NB = (N_NODES + 255) / 256;
    const int SB = (N_NODES + 1023) / 1024;
    const int MB = (N_NODES + 127) / 128;

    k_deg<<<EB, 256, 0, stream>>>(esrc, edst, deg_out, deg_in);
    k_norm<<<NB, 256, 0, stream>>>(deg_out, deg_in, ns, nd);
    k_wconv<<<HIDDEN, 640, 0, stream>>>(W1, Wt_hi, Wt_lo);
    k_scan1<<<SB, 1024, 0, stream>>>(deg_in, row_ptr, blk);
    k_scan2<<<1, 128, 0, stream>>>(blk, SB);
    k_scan3<<<NB, 256, 0, stream>>>(row_ptr, blk);
    k_fill<<<EB, 256, 0, stream>>>(esrc, edst, row_ptr, cursor, csr);
    k_gemm1<<<MB, 256, 0, stream>>>(x, Wt_hi, Wt_lo, ns, y1);
    k_spmm1<<<(N_NODES + 3) / 4, 256, 0, stream>>>(y1, row_ptr, deg_in, csr, nd, b1, h1);
    k_gemm2<<<(N_NODES + 63) / 64, 256, 0, stream>>>(h1, W2, ns, y2);
    k_spmm2<<<(N_NODES + 3) / 4, 256, 0, stream>>>(y2, row_ptr, deg_in, csr, nd, b2, out);
}